// Round 4
// baseline (153.096 us; speedup 1.0000x reference)
//
#include <hip/hip_runtime.h>

// Problem constants: B=4, T=1024, F=500, H=128, P=64
// All external buffers fp32. Internal GEMMs bf16 (fp32 MFMA accum).
// out = [probs (B*T*P=262144), all_states (T*B*H=524288)] fp32
//
// ws layout (~26.4 MB of the ~256 MB workspace):
//   x_pad   [0,         4194304)  4096x512 bf16 (K padded 500->512)
//   W_ihp   [4194304,   4587520)  384x512  bf16
//   gi_bf   [4587520,   7733248)  4096x384 bf16
//   S_bf    [7733248,   8781824)  4096x128 bf16 ([T,B,H] rows sr=t*4+b)
//   Wc      [8781824,  10878976)  64x128x128 bf16 (folded ctx weights)
//   partial [10878976, 27656192)  8 x 4096x128 fp32 (ctx split-K partials)

typedef short bf16x8 __attribute__((ext_vector_type(8)));
typedef float f32x4 __attribute__((ext_vector_type(4)));
typedef unsigned short u16;
typedef unsigned int u32;

__device__ __forceinline__ float bf2f(u16 u) {
  union { u32 i; float f; } v; v.i = ((u32)u) << 16; return v.f;
}
__device__ __forceinline__ u16 f2bf(float f) {
  union { float f; u32 i; } v; v.f = f;
  u32 u = v.i;
  return (u16)((u + 0x7FFFu + ((u >> 16) & 1u)) >> 16);
}
__device__ __forceinline__ u32 pack2(float a, float b) {
  return (u32)f2bf(a) | ((u32)f2bf(b) << 16);
}
__device__ __forceinline__ float sigmoidf_(float x) {
  return 1.0f / (1.0f + __expf(-x));
}

// blocks [0,128): Wc[p][h'][h] = W_ctx[h', 8192 + h*64 + p] (+ part1 row sums
//   folded into p==0), built via coalesced loads + LDS transpose.
// blocks [128,1248): bf16-convert & pad x (1024 blocks) and W_ih (96 blocks).
__global__ __launch_bounds__(256) void k_prep(const float* __restrict__ W_ctx,
                                              const float* __restrict__ x,
                                              const float* __restrict__ W_ih,
                                              u16* __restrict__ Wc,
                                              u16* __restrict__ x_pad,
                                              u16* __restrict__ W_ihp) {
  const int tid = threadIdx.x;
  if (blockIdx.x < 128) {
    __shared__ float t1[128][68];   // part1 [h][q], +4 pad (16B-aligned rows)
    __shared__ float t2[128][68];   // part2 [h][p]
    __shared__ float s1[128];
    const int hp = blockIdx.x;
    const float* wrow = W_ctx + hp * 16384;
    for (int it = 0; it < 8; ++it) {   // 2048 float4 each half, coalesced
      int i = it * 256 + tid;
      int j = i * 4;
      int h = j >> 6, q = j & 63;
      *(float4*)&t1[h][q] = *(const float4*)(wrow + j);
      *(float4*)&t2[h][q] = *(const float4*)(wrow + 8192 + j);
    }
    __syncthreads();
    if (tid < 128) {
      float s = 0.f;
      for (int q = 0; q < 64; ++q) s += t1[tid][q];
      s1[tid] = s;
    }
    __syncthreads();
    for (int it = 0; it < 8; ++it) {   // write 64p x 128h bf16, coalesced uint2
      int i = it * 256 + tid;
      int p = i >> 5, h0 = (i & 31) * 4;
      float v0 = t2[h0 + 0][p], v1 = t2[h0 + 1][p];
      float v2 = t2[h0 + 2][p], v3 = t2[h0 + 3][p];
      if (p == 0) { v0 += s1[h0]; v1 += s1[h0 + 1]; v2 += s1[h0 + 2]; v3 += s1[h0 + 3]; }
      uint2 o; o.x = pack2(v0, v1); o.y = pack2(v2, v3);
      *(uint2*)(Wc + p * 16384 + hp * 128 + h0) = o;
    }
  } else {
    int idx = (blockIdx.x - 128) * 256 + tid;   // 286720 total = 262144 + 24576
    const float* src; u16* dst; int row, c8;
    if (idx < 262144) { row = idx >> 6; c8 = (idx & 63) * 8; src = x;   dst = x_pad; }
    else { idx -= 262144; row = idx >> 6; c8 = (idx & 63) * 8; src = W_ih; dst = W_ihp; }
    float4 a = make_float4(0.f, 0.f, 0.f, 0.f), b = a;
    if (c8 < 500)     a = *(const float4*)(src + (size_t)row * 500 + c8);
    if (c8 + 4 < 500) b = *(const float4*)(src + (size_t)row * 500 + c8 + 4);
    uint4 o; o.x = pack2(a.x, a.y); o.y = pack2(a.z, a.w);
    o.z = pack2(b.x, b.y); o.w = pack2(b.z, b.w);
    *(uint4*)(dst + (size_t)row * 512 + c8) = o;
  }
}

// gi = x_pad @ W_ihp^T  (M=4096, N=384, K=512). 64x64 tiles, grid (64,6).
// Register prefetch of next K-block overlaps MFMA.
__global__ __launch_bounds__(256) void k_gemm_gi(const u16* __restrict__ A,
                                                 const u16* __restrict__ Bw,
                                                 u16* __restrict__ gi_bf) {
  __shared__ u16 Asm[64][136];
  __shared__ u16 Bsm[64][136];
  const int tid = threadIdx.x;
  const int r0 = blockIdx.x * 64;
  const int n0 = blockIdx.y * 64;
  const int lane = tid & 63, w = tid >> 6;
  const int l15 = lane & 15, quad = lane >> 4;
  const int srow = tid >> 4, scol = (tid & 15) * 8;   // staging: 16 rows/64 iter grp
  f32x4 acc[4];
  for (int i = 0; i < 4; ++i) acc[i] = (f32x4){0.f, 0.f, 0.f, 0.f};

  uint4 pa[4], pb[4];
#pragma unroll
  for (int it = 0; it < 4; ++it) {
    pa[it] = *(const uint4*)(A + (size_t)(r0 + it * 16 + srow) * 512 + scol);
    pb[it] = *(const uint4*)(Bw + (size_t)(n0 + it * 16 + srow) * 512 + scol);
  }
  for (int kb = 0; kb < 4; ++kb) {
    if (kb > 0) __syncthreads();
#pragma unroll
    for (int it = 0; it < 4; ++it) {
      *(uint4*)&Asm[it * 16 + srow][scol] = pa[it];
      *(uint4*)&Bsm[it * 16 + srow][scol] = pb[it];
    }
    __syncthreads();
    if (kb < 3) {
      int kg = (kb + 1) * 128;
#pragma unroll
      for (int it = 0; it < 4; ++it) {
        pa[it] = *(const uint4*)(A + (size_t)(r0 + it * 16 + srow) * 512 + kg + scol);
        pb[it] = *(const uint4*)(Bw + (size_t)(n0 + it * 16 + srow) * 512 + kg + scol);
      }
    }
#pragma unroll
    for (int kk = 0; kk < 4; ++kk) {
      int kbase = kk * 32 + quad * 8;
      bf16x8 bf = *(const bf16x8*)&Bsm[w * 16 + l15][kbase];
#pragma unroll
      for (int mt = 0; mt < 4; ++mt) {
        bf16x8 af = *(const bf16x8*)&Asm[mt * 16 + l15][kbase];
        acc[mt] = __builtin_amdgcn_mfma_f32_16x16x32_bf16(af, bf, acc[mt], 0, 0, 0);
      }
    }
  }
  for (int mt = 0; mt < 4; ++mt)
    for (int rg = 0; rg < 4; ++rg) {
      int m = r0 + mt * 16 + quad * 4 + rg;
      int n = n0 + w * 16 + l15;
      gi_bf[m * 384 + n] = f2bf(acc[mt][rg]);
    }
}

// GRU gates with h=0: s = (1-sig(gz+bz)) * tanh(gn + sig(gr+br)*bn_hh).
__global__ void k_states(const u16* __restrict__ gi_bf,
                         const float* __restrict__ b_ih, const float* __restrict__ b_hh,
                         u16* __restrict__ S_bf, float* __restrict__ out_states) {
  int g = blockIdx.x * 256 + threadIdx.x;  // 4096*128
  int r = g >> 7, h = g & 127;
  float xr = bf2f(gi_bf[r * 384 + h])       + b_ih[h]       + b_hh[h];
  float xz = bf2f(gi_bf[r * 384 + 128 + h]) + b_ih[128 + h] + b_hh[128 + h];
  float xn = bf2f(gi_bf[r * 384 + 256 + h]) + b_ih[256 + h];
  float rg = sigmoidf_(xr);
  float zg = sigmoidf_(xz);
  float n = tanhf(xn + rg * b_hh[256 + h]);
  float s = (1.f - zg) * n;
  int b = r >> 10, t = r & 1023;
  S_bf[(t * 4 + b) * 128 + h] = f2bf(s);
  out_states[(t * 4 + b) * 128 + h] = s;
}

// Context GEMM, split-K over p-chunks of 8. A (shifted states) staged ONCE per
// block into a 96-row shared window (p-shifts overlap); B prefetch-pipelined.
// partial[chunk] = sum_{p in chunk} Wc_p @ s[max(t-p,0), b].
__global__ __launch_bounds__(256) void k_gemm_ctx(const u16* __restrict__ S_bf,
                                                  const u16* __restrict__ Wc,
                                                  float* __restrict__ partial) {
  __shared__ u16 Asm[96][136];
  __shared__ u16 Bsm[128][136];
  const int tid = threadIdx.x;
  const int r0 = blockIdx.x * 64;      // t0 = r0/4
  const int P0 = blockIdx.y * 8;
  const int t0 = r0 >> 2;
  int tlo = t0 - P0 - 7; if (tlo < 0) tlo = 0;
  const int lane = tid & 63, w = tid >> 6;
  const int l15 = lane & 15, quad = lane >> 4;
  const int srow = tid >> 4, scol = (tid & 15) * 8;
  f32x4 acc[4][2];
  for (int i = 0; i < 4; ++i)
    for (int j = 0; j < 2; ++j) acc[i][j] = (f32x4){0.f, 0.f, 0.f, 0.f};

  // Stage A window: rows i -> (t = min(tlo + i/4, 1023), b = i&3), 96 rows.
  uint4 pa[6];
#pragma unroll
  for (int it = 0; it < 6; ++it) {
    int row = it * 16 + srow;
    int ti = tlo + (row >> 2); if (ti > 1023) ti = 1023;
    int gr = ti * 4 + (row & 3);
    pa[it] = *(const uint4*)(S_bf + (size_t)gr * 128 + scol);
  }
  uint4 pb[8];
#pragma unroll
  for (int it = 0; it < 8; ++it)
    pb[it] = *(const uint4*)(Wc + (size_t)P0 * 16384 + (it * 16 + srow) * 128 + scol);
#pragma unroll
  for (int it = 0; it < 6; ++it) *(uint4*)&Asm[it * 16 + srow][scol] = pa[it];
#pragma unroll
  for (int it = 0; it < 8; ++it) *(uint4*)&Bsm[it * 16 + srow][scol] = pb[it];
  __syncthreads();

  for (int pi = 0; pi < 8; ++pi) {
    int p = P0 + pi;
    if (pi < 7) {
#pragma unroll
      for (int it = 0; it < 8; ++it)
        pb[it] = *(const uint4*)(Wc + (size_t)(p + 1) * 16384 + (it * 16 + srow) * 128 + scol);
    }
    // A-row LDS indices for this p (per mt; lane's m-row = r0 + mt*16 + l15)
    int lrow[4];
#pragma unroll
    for (int mt = 0; mt < 4; ++mt) {
      int rA = r0 + mt * 16 + l15;
      int tp = (rA >> 2) - p; if (tp < 0) tp = 0;
      lrow[mt] = (tp - tlo) * 4 + (rA & 3);
    }
#pragma unroll
    for (int kk = 0; kk < 4; ++kk) {
      int kbase = kk * 32 + quad * 8;
      bf16x8 b0 = *(const bf16x8*)&Bsm[w * 32 + l15][kbase];
      bf16x8 b1 = *(const bf16x8*)&Bsm[w * 32 + 16 + l15][kbase];
#pragma unroll
      for (int mt = 0; mt < 4; ++mt) {
        bf16x8 af = *(const bf16x8*)&Asm[lrow[mt]][kbase];
        acc[mt][0] = __builtin_amdgcn_mfma_f32_16x16x32_bf16(af, b0, acc[mt][0], 0, 0, 0);
        acc[mt][1] = __builtin_amdgcn_mfma_f32_16x16x32_bf16(af, b1, acc[mt][1], 0, 0, 0);
      }
    }
    if (pi < 7) {
      __syncthreads();
#pragma unroll
      for (int it = 0; it < 8; ++it) *(uint4*)&Bsm[it * 16 + srow][scol] = pb[it];
      __syncthreads();
    }
  }
  float* outp = partial + (size_t)blockIdx.y * (4096 * 128);
  for (int mt = 0; mt < 4; ++mt)
    for (int nt = 0; nt < 2; ++nt)
      for (int rg = 0; rg < 4; ++rg) {
        int m = r0 + mt * 16 + quad * 4 + rg;
        int n = w * 32 + nt * 16 + l15;
        outp[m * 128 + n] = acc[mt][nt][rg];
      }
}

// Reduce partials + b_ctx -> sigmoid gate; gated = states(fp32)*gate; FC+sig+clip.
__global__ __launch_bounds__(256) void k_epilogue(const float* __restrict__ partial,
                                                  const float* __restrict__ states,
                                                  const float* __restrict__ b_ctx,
                                                  const float* __restrict__ W_fc,
                                                  const float* __restrict__ b_fc,
                                                  float* __restrict__ out_probs) {
  __shared__ float WfcT[128][68];   // [h][p'], transposed: dot reads conflict-free
  __shared__ float gated[8][128];
  const int tid = threadIdx.x;
  const int row0 = blockIdx.x * 8;
  for (int it = 0; it < 32; ++it) {
    int i = it * 256 + tid;
    int pp = i >> 7, h = i & 127;
    WfcT[h][pp] = W_fc[i];
  }
  for (int it = 0; it < 4; ++it) {
    int i = it * 256 + tid;
    int lr = i >> 7, h = i & 127;
    int sr = row0 + lr;
    float gp = b_ctx[h];
#pragma unroll
    for (int c = 0; c < 8; ++c) gp += partial[(size_t)c * (4096 * 128) + sr * 128 + h];
    gated[lr][h] = states[sr * 128 + h] * sigmoidf_(gp);
  }
  __syncthreads();
  for (int it = 0; it < 2; ++it) {
    int o = it * 256 + tid;
    int lr = o >> 6, pp = o & 63;
    int sr = row0 + lr;
    float dot = 0.f;
#pragma unroll
    for (int h = 0; h < 128; ++h) dot += gated[lr][h] * WfcT[h][pp];
    float pv = sigmoidf_(dot + b_fc[pp]);
    pv = (pv > 0.001f) ? pv : 0.001f;
    pv = (pv < 0.999f) ? pv : 0.999f;
    int t = sr >> 2, b = sr & 3;
    out_probs[(b * 1024 + t) * 64 + pp] = pv;
  }
}

extern "C" void kernel_launch(void* const* d_in, const int* in_sizes, int n_in,
                              void* d_out, int out_size, void* d_ws, size_t ws_size,
                              hipStream_t stream) {
  const float* x     = (const float*)d_in[0];
  const float* W_ih  = (const float*)d_in[1];
  // d_in[2] = W_hh: unused (hidden state is always 0 in the reference)
  const float* b_ih  = (const float*)d_in[3];
  const float* b_hh  = (const float*)d_in[4];
  const float* W_ctx = (const float*)d_in[5];
  const float* b_ctx = (const float*)d_in[6];
  const float* W_fc  = (const float*)d_in[7];
  const float* b_fc  = (const float*)d_in[8];
  float* out = (float*)d_out;

  char* ws = (char*)d_ws;
  u16*   x_pad   = (u16*)  (ws + 0);           // 4,194,304 B
  u16*   W_ihp   = (u16*)  (ws + 4194304);     //   393,216 B
  u16*   gi_bf   = (u16*)  (ws + 4587520);     // 3,145,728 B
  u16*   S_bf    = (u16*)  (ws + 7733248);     // 1,048,576 B
  u16*   Wc      = (u16*)  (ws + 8781824);     // 2,097,152 B
  float* partial = (float*)(ws + 10878976);    // 16,777,216 B
  // total ws used: 27,656,192 bytes

  k_prep<<<1248, 256, 0, stream>>>(W_ctx, x, W_ih, Wc, x_pad, W_ihp);
  k_gemm_gi<<<dim3(64, 6), 256, 0, stream>>>(x_pad, W_ihp, gi_bf);
  k_states<<<2048, 256, 0, stream>>>(gi_bf, b_ih, b_hh, S_bf, out + 262144);
  k_gemm_ctx<<<dim3(64, 8), 256, 0, stream>>>(S_bf, Wc, partial);
  k_epilogue<<<512, 256, 0, stream>>>(partial, out + 262144, b_ctx, W_fc, b_fc, out);
}